// Round 4
// baseline (394.007 us; speedup 1.0000x reference)
//
#include <hip/hip_runtime.h>

#define NPIX (1024 * 1024)
#define NBATCH 16
#define SUBPB 64      // sub-histogram blocks per batch
#define NBINS 8192
#define HTHREADS 512

typedef float vfloat4 __attribute__((ext_vector_type(4)));

// ---------------------------------------------------------------------------
// Kernel 1: per-block LDS histogram, private non-atomic flush.
// R3 change: explicit 2-deep load batching -> 6 independent float4 loads
// (96 B/lane) in flight before any compute, instead of 3 + compiler luck.
// 1024 blocks x 512 thr = 4 blocks/CU x 8 waves = 32 waves/CU.
// ---------------------------------------------------------------------------
__global__ __launch_bounds__(HTHREADS) void hist_kernel(
        const float* __restrict__ img,
        const float* __restrict__ rgb2yuv,
        unsigned int* __restrict__ ghist) {
    __shared__ unsigned int lh[NBINS];
    for (int i = threadIdx.x; i < NBINS; i += HTHREADS) lh[i] = 0;
    const float c0 = rgb2yuv[0];
    const float c1 = rgb2yuv[1];
    const float c2 = rgb2yuv[2];
    __syncthreads();

    const int b = blockIdx.x / SUBPB;
    const int s = blockIdx.x % SUBPB;
    const int pixPerBlock = NPIX / SUBPB;  // 16384
    const size_t base = (size_t)b * 3 * NPIX + (size_t)s * pixPerBlock;

    const float4* r4 = (const float4*)(img + base);
    const float4* g4 = (const float4*)(img + base + NPIX);
    const float4* b4 = (const float4*)(img + base + 2 * (size_t)NPIX);
    const int n4 = pixPerBlock / 4;  // 4096 -> 4 double-iters/thread

    const float scale = (float)NBINS;
    for (int i = threadIdx.x; i < n4; i += 2 * HTHREADS) {
        // 6 independent loads issued back-to-back (96 B per lane in flight)
        float4 R0 = r4[i];
        float4 R1 = r4[i + HTHREADS];
        float4 G0 = g4[i];
        float4 G1 = g4[i + HTHREADS];
        float4 B0 = b4[i];
        float4 B1 = b4[i + HTHREADS];

        float y0 = c0 * R0.x + c1 * G0.x + c2 * B0.x;
        float y1 = c0 * R0.y + c1 * G0.y + c2 * B0.y;
        float y2 = c0 * R0.z + c1 * G0.z + c2 * B0.z;
        float y3 = c0 * R0.w + c1 * G0.w + c2 * B0.w;
        float y4 = c0 * R1.x + c1 * G1.x + c2 * B1.x;
        float y5 = c0 * R1.y + c1 * G1.y + c2 * B1.y;
        float y6 = c0 * R1.z + c1 * G1.z + c2 * B1.z;
        float y7 = c0 * R1.w + c1 * G1.w + c2 * B1.w;

        int i0 = min(NBINS - 1, max(0, (int)(y0 * scale)));
        int i1 = min(NBINS - 1, max(0, (int)(y1 * scale)));
        int i2 = min(NBINS - 1, max(0, (int)(y2 * scale)));
        int i3 = min(NBINS - 1, max(0, (int)(y3 * scale)));
        int i4 = min(NBINS - 1, max(0, (int)(y4 * scale)));
        int i5 = min(NBINS - 1, max(0, (int)(y5 * scale)));
        int i6 = min(NBINS - 1, max(0, (int)(y6 * scale)));
        int i7 = min(NBINS - 1, max(0, (int)(y7 * scale)));

        atomicAdd(&lh[i0], 1u);
        atomicAdd(&lh[i1], 1u);
        atomicAdd(&lh[i2], 1u);
        atomicAdd(&lh[i3], 1u);
        atomicAdd(&lh[i4], 1u);
        atomicAdd(&lh[i5], 1u);
        atomicAdd(&lh[i6], 1u);
        atomicAdd(&lh[i7], 1u);
    }
    __syncthreads();

    // Non-atomic flush of the private histogram (fully overwrites its slot,
    // so no pre-zeroing of ghist is needed).
    uint4* dst = (uint4*)(ghist + (size_t)blockIdx.x * NBINS);
    const uint4* src = (const uint4*)lh;
    for (int i = threadIdx.x; i < NBINS / 4; i += HTHREADS) dst[i] = src[i];
}

// ---------------------------------------------------------------------------
// Kernel 2: one block per batch. Reduce the 64 sub-histograms (coalesced
// uint4 loads), scan, locate the 4 order statistics
// (10485,10486 / 1038089,1038090), interpolate, write (blkpt, mult).
// ---------------------------------------------------------------------------
__global__ __launch_bounds__(1024) void scan_kernel(
        const unsigned int* __restrict__ ghist,
        float* __restrict__ stats) {
    __shared__ unsigned int hist[NBINS];
    __shared__ unsigned int segsum[1024];
    __shared__ float vals[4];

    const int b = blockIdx.x;
    const int t = threadIdx.x;

    unsigned int a[8] = {0u, 0u, 0u, 0u, 0u, 0u, 0u, 0u};
    for (int s = 0; s < SUBPB; ++s) {
        const uint4* p =
            (const uint4*)(ghist + ((size_t)b * SUBPB + s) * NBINS + t * 8);
        uint4 v0 = p[0];
        uint4 v1 = p[1];
        a[0] += v0.x; a[1] += v0.y; a[2] += v0.z; a[3] += v0.w;
        a[4] += v1.x; a[5] += v1.y; a[6] += v1.z; a[7] += v1.w;
    }
    unsigned int ss = 0;
#pragma unroll
    for (int j = 0; j < 8; ++j) {
        hist[t * 8 + j] = a[j];
        ss += a[j];
    }
    segsum[t] = ss;
    __syncthreads();

    for (int off = 1; off < 1024; off <<= 1) {
        unsigned int v = segsum[t];
        unsigned int add = (t >= off) ? segsum[t - off] : 0u;
        __syncthreads();
        segsum[t] = v + add;
        __syncthreads();
    }

    const unsigned int cumincl = segsum[t];
    const unsigned int cumbefore = (t > 0) ? segsum[t - 1] : 0u;

    const unsigned int ranks[4] = {10485u, 10486u, 1038089u, 1038090u};
    const int BPT = NBINS / 1024;  // 8
#pragma unroll
    for (int q = 0; q < 4; ++q) {
        unsigned int r = ranks[q];
        if (r >= cumbefore && r < cumincl) {
            unsigned int running = cumbefore;
#pragma unroll
            for (int j = 0; j < BPT; ++j) {
                unsigned int c = hist[t * BPT + j];
                if (r < running + c) {
                    float v = ((float)(t * BPT + j) +
                               ((float)(r - running) + 0.5f) / (float)c) *
                              (1.0f / (float)NBINS);
                    vals[q] = v;
                    break;
                }
                running += c;
            }
        }
    }
    __syncthreads();

    if (t == 0) {
        float blk = 0.25f * vals[0] + 0.75f * vals[1];
        float wht = 0.75f * vals[2] + 0.25f * vals[3];
        float mult = fminf(1.0f / (wht - blk), 1.5f);
        stats[b * 2 + 0] = blk;
        stats[b * 2 + 1] = mult;
    }
}

// ---------------------------------------------------------------------------
// Kernel 3: out = clip((img - blk[b]) * mult[b], 0, 1).
// R3 change: PLAIN stores (first clean NT-vs-plain A/B — NT was never
// isolated; the plain-store fill kernel demonstrably hits 6.5 TB/s).
// All 4 loads issued before compute for ILP.
// ---------------------------------------------------------------------------
__global__ __launch_bounds__(256) void apply_kernel(
        const float* __restrict__ img,
        const float* __restrict__ stats,
        float* __restrict__ out) {
    const int blocksPerBatch = (3 * NPIX / 4) / 1024;  // 768
    const int b = blockIdx.x / blocksPerBatch;
    const int c = blockIdx.x % blocksPerBatch;
    const float blk = stats[b * 2 + 0];
    const float mult = stats[b * 2 + 1];

    const vfloat4* in4 =
        (const vfloat4*)(img + (size_t)b * 3 * NPIX) + (size_t)c * 1024;
    vfloat4* out4 = (vfloat4*)(out + (size_t)b * 3 * NPIX) + (size_t)c * 1024;

    const int t = threadIdx.x;
    vfloat4 v0 = in4[t];
    vfloat4 v1 = in4[t + 256];
    vfloat4 v2 = in4[t + 512];
    vfloat4 v3 = in4[t + 768];

#define CLIP1(vv)                                          \
    vv.x = fminf(fmaxf((vv.x - blk) * mult, 0.0f), 1.0f);  \
    vv.y = fminf(fmaxf((vv.y - blk) * mult, 0.0f), 1.0f);  \
    vv.z = fminf(fmaxf((vv.z - blk) * mult, 0.0f), 1.0f);  \
    vv.w = fminf(fmaxf((vv.w - blk) * mult, 0.0f), 1.0f)
    CLIP1(v0);
    CLIP1(v1);
    CLIP1(v2);
    CLIP1(v3);
#undef CLIP1

    out4[t] = v0;
    out4[t + 256] = v1;
    out4[t + 512] = v2;
    out4[t + 768] = v3;
}

extern "C" void kernel_launch(void* const* d_in, const int* in_sizes, int n_in,
                              void* d_out, int out_size, void* d_ws, size_t ws_size,
                              hipStream_t stream) {
    const float* img = (const float*)d_in[0];
    const float* rgb2yuv = (const float*)d_in[1];
    float* out = (float*)d_out;

    // Workspace layout: [0,128): stats (16 * {blk, mult});
    // [256, 256 + 1024*8192*4): per-block sub-histograms (32 MB).
    float* stats = (float*)d_ws;
    unsigned int* ghist = (unsigned int*)((char*)d_ws + 256);

    hist_kernel<<<NBATCH * SUBPB, HTHREADS, 0, stream>>>(img, rgb2yuv, ghist);
    scan_kernel<<<NBATCH, 1024, 0, stream>>>(ghist, stats);

    const int applyBlocks = NBATCH * ((3 * NPIX / 4) / 1024);  // 12288
    apply_kernel<<<applyBlocks, 256, 0, stream>>>(img, stats, out);
}